// Round 8
// baseline (89.999 us; speedup 1.0000x reference)
//
#include <hip/hip_runtime.h>
#include <hip/hip_bf16.h>

// NeRF surrogate renderer, MI355X — round 8: MFMA reformulation.
// R3-R7: four VALU structures all ~65us -> VALU-pipe plateau. Move the MLPs to
// matrix cores: per 16-sample tile, GEMM1 = W1ext[64ux8f]·feat[8fx16s] (K=32,
// zero-padded A), relu, GEMM2 = W2ext[16ox64u]·trunk[64ux16s] (2 K=32 chunks).
// Weight fragments are loop-invariant VGPRs (prep kernel emits frag-ready
// dwords). D1->B2 transpose: bf16 pair packs + ds_bpermute (verified layouts:
// D col=lane&15,row=(lane>>4)*4+reg; A/B row|col=lane&15,k=(lane>>4)*8+i).
// One wave per ray; outputs stashed in per-wave LDS; per-lane composite of 2
// samples + width-64 transmittance scan.

typedef float  f32x4  __attribute__((ext_vector_type(4)));
typedef short  bf16x8 __attribute__((ext_vector_type(8)));
typedef unsigned int u32;

__device__ __forceinline__ float fast_rcp(float x){ return __builtin_amdgcn_rcpf(x); }
__device__ __forceinline__ float softplus_f(float x){
    float e = __expf(-fabsf(x));
    return fmaxf(x,0.f) + __logf(1.f+e);
}
__device__ __forceinline__ float sigmoid_f(float x){ return fast_rcp(1.f+__expf(-x)); }

__device__ __forceinline__ u32 bfr_hi(float f){   // RNE bf16, kept in high half
    u32 u = __float_as_uint(f);
    return (u + 0x7FFFu + ((u>>16)&1u)) & 0xFFFF0000u;
}
__device__ __forceinline__ u32 pkbf(float lo, float hi){
    return (bfr_hi(lo)>>16) | bfr_hi(hi);
}

// ---- prep: emit fragment-ready bf16 dword images into d_ws ----
// ws[0..1023]    : A1 frags, [ut(4)][lane(64)][dw(4)]  (GEMM1 A = W1ext)
// ws[1024..1535] : A2 frags, [ch(2)][lane(64)][dw(4)]  (GEMM2 A = W2ext)
__global__ __launch_bounds__(256)
void nerf_prep_kernel(const float* __restrict__ W1, const float* __restrict__ b1,
                      const float* __restrict__ Wsig, const float* __restrict__ Wsig_d,
                      const float* __restrict__ Wc1, const float* __restrict__ bc1,
                      const float* __restrict__ Wc2, const float* __restrict__ Wc2_d,
                      u32* __restrict__ ws)
{
    const int q0 = threadIdx.x;
#pragma unroll
    for (int k = 0; k < 6; ++k) {
        const int q = q0 + k*256;          // 0..1535
        u32 val = 0u;
        if (q < 1024) {                    // A1: row m=unit (lane&15), k=8g+i feats
            const int ut = q>>8, rem = q&255, lane = rem>>2, dw = rem&3;
            const int g = lane>>4, m = lane&15;
            if (g == 0) {                  // k>=8 lanes stay zero (K padding)
                float w[8];
                if (ut < 2) { const int u = ut*16 + m;
                    w[0]=W1[u];  w[1]=W1[32+u];  w[2]=W1[64+u];  w[3]=b1[u];
                    w[4]=0.f;    w[5]=0.f;       w[6]=0.f;       w[7]=0.f;
                } else {        const int u = (ut-2)*16 + m;
                    w[0]=Wc1[u]; w[1]=Wc1[32+u]; w[2]=Wc1[64+u]; w[3]=bc1[u];
                    w[4]=Wc1[96+u]; w[5]=Wc1[128+u]; w[6]=Wc1[160+u]; w[7]=0.f;
                }
                val = pkbf(w[2*dw], w[2*dw+1]);
            }
        } else {                           // A2: row o=output (lane&15), k=units
            const int q2 = q-1024, ch = q2>>8, rem = q2&255, lane = rem>>2, dw = rem&3;
            const int g = lane>>4, o = lane&15;
            float w[2];
#pragma unroll
            for (int e = 0; e < 2; ++e) {
                const int u = ch*32 + g*8 + 2*dw + e;
                float v = 0.f;
                if (u < 32) {              // h-trunk units -> sigma heads
                    if (o == 0) v = Wsig[u];
                    else if (o == 1) v = Wsig_d[u];
                } else {                   // hc-trunk units -> color heads
                    const int up = u - 32;
                    if (o >= 2 && o <= 4) v = Wc2[up*3 + (o-2)];
                    else if (o >= 5 && o <= 7) v = Wc2_d[up*3 + (o-5)];
                }
                w[e] = v;
            }
            val = pkbf(w[0], w[1]);
        }
        ws[q] = val;
    }
}

// ---- main: 1 wave per ray, 4 rays per 256-thread block ----
__global__ __launch_bounds__(256, 4)
void nerf_render_kernel(const float* __restrict__ rays_o,
                        const float* __restrict__ rays_d,
                        const u32*  __restrict__ wsm,
                        const int*  __restrict__ num_steps,
                        float* __restrict__ out,
                        int N)
{
    __shared__ __align__(16) float stash[4][128*8];   // per-wave [t][8 outs]

    const int tid  = threadIdx.x;
    const int wid  = tid>>6, lane = tid&63;
    const int ray  = blockIdx.x*4 + wid;
    if (ray >= N) return;
    const int T = num_steps[0];
    const int g = lane>>4, c = lane&15;

    // loop-invariant weight fragments
    const uint4* wsv = (const uint4*)wsm;
    uint4 a1u[4], a2u[2];
#pragma unroll
    for (int ut = 0; ut < 4; ++ut) a1u[ut] = wsv[ut*64 + lane];
#pragma unroll
    for (int ch = 0; ch < 2; ++ch) a2u[ch] = wsv[256 + ch*64 + lane];

    // ray setup
    const float ox = rays_o[ray*3+0], oy = rays_o[ray*3+1], oz = rays_o[ray*3+2];
    const float rdx = rays_d[ray*3+0], rdy = rays_d[ray*3+1], rdz = rays_d[ray*3+2];
    const float rn = rsqrtf(rdx*rdx + rdy*rdy + rdz*rdz);
    const float dx = rdx*rn, dy = rdy*rn, dz = rdz*rn;

    const float ix = 1.0f/dx, iy = 1.0f/dy, iz = 1.0f/dz;
    const float t1x = (-1.f-ox)*ix, t2x = (1.f-ox)*ix;
    const float t1y = (-1.f-oy)*iy, t2y = (1.f-oy)*iy;
    const float t1z = (-1.f-oz)*iz, t2z = (1.f-oz)*iz;
    float nearv = fmaxf(fmaxf(fminf(t1x,t2x), fminf(t1y,t2y)), fminf(t1z,t2z));
    float farv  = fminf(fminf(fmaxf(t1x,t2x), fmaxf(t1y,t2y)), fmaxf(t1z,t2z));
    nearv = fmaxf(nearv, 0.2f);
    farv  = fmaxf(farv, nearv + 1e-6f);

    const float span    = farv - nearv;
    const float stepz   = (T > 1) ? span/(float)(T-1) : 0.f;
    const float inv_tm1 = (T > 1) ? 1.f/(float)(T-1) : 0.f;
    const float last_dt = span/(float)T;

    const u32 dirw0 = pkbf(dx, dy);
    const u32 dirw1 = pkbf(dz, 0.f);

    // bpermute source-lane byte indices for the D1->B2 transpose
    const int idx01 = ((g&1)*32 + c)*4;   // source group 2*(g&1)
    const int idx23 = idx01 + 64;         // source group 2*(g&1)+1
    const bool glo  = (g < 2);            // dest g<2 pulls even tile, else odd

    float* sb = stash[wid];
    int ntiles = (T + 15) >> 4;
    if (ntiles > 8) ntiles = 8;

    for (int tt = 0; tt < ntiles; ++tt) {
        const int t0 = tt*16;
        // B1 fragment: col=sample c, k=feats [x,y,z,1,dx,dy,dz,0] (bf16)
        const float zv = fmaf(stepz, (float)(t0 + c), nearv);
        const float X = fminf(fmaxf(fmaf(dx, zv, ox), -1.f), 1.f);
        const float Y = fminf(fmaxf(fmaf(dy, zv, oy), -1.f), 1.f);
        const float Z = fminf(fmaxf(fmaf(dz, zv, oz), -1.f), 1.f);
        uint4 b1u;
        b1u.x = pkbf(X, Y);
        b1u.y = pkbf(Z, 1.0f);
        b1u.z = dirw0;
        b1u.w = dirw1;
        const bf16x8 b1f = __builtin_bit_cast(bf16x8, b1u);

        // GEMM1: trunk[64 units][16 samples]
        f32x4 acc1[4];
#pragma unroll
        for (int ut = 0; ut < 4; ++ut) {
            acc1[ut] = __builtin_amdgcn_mfma_f32_16x16x32_bf16(
                __builtin_bit_cast(bf16x8, a1u[ut]), b1f,
                (f32x4){0.f,0.f,0.f,0.f}, 0, 0, 0);
        }

        // relu + bf16 pair packs: p0 = units(4g+0,1), p1 = units(4g+2,3) per tile
        u32 p0[4], p1[4];
#pragma unroll
        for (int ut = 0; ut < 4; ++ut) {
            const float v0 = fmaxf(acc1[ut].x, 0.f);
            const float v1 = fmaxf(acc1[ut].y, 0.f);
            const float v2 = fmaxf(acc1[ut].z, 0.f);
            const float v3 = fmaxf(acc1[ut].w, 0.f);
            p0[ut] = pkbf(v0, v1);
            p1[ut] = pkbf(v2, v3);
        }

        // GEMM2: out[16 outs][16 samples], K=64 units in 2 chunks of 32
        f32x4 acc2 = {0.f,0.f,0.f,0.f};
#pragma unroll
        for (int ch = 0; ch < 2; ++ch) {
            const int te = 2*ch, to = te+1;
            const u32 e0 = (u32)__builtin_amdgcn_ds_bpermute(idx01, (int)p0[te]);
            const u32 o0 = (u32)__builtin_amdgcn_ds_bpermute(idx01, (int)p0[to]);
            const u32 e1 = (u32)__builtin_amdgcn_ds_bpermute(idx01, (int)p1[te]);
            const u32 o1 = (u32)__builtin_amdgcn_ds_bpermute(idx01, (int)p1[to]);
            const u32 e2 = (u32)__builtin_amdgcn_ds_bpermute(idx23, (int)p0[te]);
            const u32 o2 = (u32)__builtin_amdgcn_ds_bpermute(idx23, (int)p0[to]);
            const u32 e3 = (u32)__builtin_amdgcn_ds_bpermute(idx23, (int)p1[te]);
            const u32 o3 = (u32)__builtin_amdgcn_ds_bpermute(idx23, (int)p1[to]);
            uint4 b2u;
            b2u.x = glo ? e0 : o0;
            b2u.y = glo ? e1 : o1;
            b2u.z = glo ? e2 : o2;
            b2u.w = glo ? e3 : o3;
            acc2 = __builtin_amdgcn_mfma_f32_16x16x32_bf16(
                __builtin_bit_cast(bf16x8, a2u[ch]),
                __builtin_bit_cast(bf16x8, b2u), acc2, 0, 0, 0);
        }

        // stash: g=0 -> outs 0..3 (sA,sD,r0A,r1A); g=1 -> outs 4..7 (r2A,r0D,r1D,r2D)
        if (g < 2) {
            *(f32x4*)&sb[(t0 + c)*8 + g*4] = acc2;
        }
    }

    // epilogue: lane owns samples [lane*spl, lane*spl+spl)
    float iA0=0.f,iA1=0.f,iA2=0.f,dAc=0.f,wsA=0.f,TAx=1.f;
    float iD0=0.f,iD1=0.f,iD2=0.f,dDc=0.f,wsD=0.f,TDx=1.f;
    const int spl = (T + 63) >> 6;
    for (int k2 = 0; k2 < spl; ++k2) {
        const int t = lane*spl + k2;
        if (t < T) {
            const f32x4 oA = *(const f32x4*)&sb[t*8];
            const f32x4 oB = *(const f32x4*)&sb[t*8 + 4];
            const float dneg = (t < T-1) ? -stepz : -last_dt;
            const float z01  = (float)t * inv_tm1;

            const float sigA = softplus_f(oA.x);
            const float qA = __expf(dneg*sigA);
            const float wA = TAx - TAx*qA; TAx *= qA;
            iA0 = fmaf(wA, sigmoid_f(oA.z), iA0);
            iA1 = fmaf(wA, sigmoid_f(oA.w), iA1);
            iA2 = fmaf(wA, sigmoid_f(oB.x), iA2);
            dAc = fmaf(wA, z01, dAc); wsA += wA;

            const float sigD = softplus_f(oA.y);
            const float qD = __expf(dneg*sigD);
            const float wD = TDx - TDx*qD; TDx *= qD;
            iD0 = fmaf(wD, sigmoid_f(oB.y), iD0);
            iD1 = fmaf(wD, sigmoid_f(oB.z), iD1);
            iD2 = fmaf(wD, sigmoid_f(oB.w), iD2);
            dDc = fmaf(wD, z01, dDc); wsD += wD;
        }
    }

    // width-64 exclusive prefix product of transmittance, scale, butterfly-sum
    float scanA = TAx, scanD = TDx;
#pragma unroll
    for (int off = 1; off < 64; off <<= 1) {
        const float tA_ = __shfl_up(scanA, off, 64);
        const float tD_ = __shfl_up(scanD, off, 64);
        if (lane >= off) { scanA *= tA_; scanD *= tD_; }
    }
    float exA = __shfl_up(scanA, 1, 64);
    float exD = __shfl_up(scanD, 1, 64);
    if (lane == 0) { exA = 1.f; exD = 1.f; }

    iA0 *= exA; iA1 *= exA; iA2 *= exA; dAc *= exA; wsA *= exA;
    iD0 *= exD; iD1 *= exD; iD2 *= exD; dDc *= exD; wsD *= exD;

#pragma unroll
    for (int mask = 1; mask < 64; mask <<= 1) {
        iA0 += __shfl_xor(iA0, mask, 64);
        iA1 += __shfl_xor(iA1, mask, 64);
        iA2 += __shfl_xor(iA2, mask, 64);
        dAc += __shfl_xor(dAc, mask, 64);
        wsA += __shfl_xor(wsA, mask, 64);
        iD0 += __shfl_xor(iD0, mask, 64);
        iD1 += __shfl_xor(iD1, mask, 64);
        iD2 += __shfl_xor(iD2, mask, 64);
        dDc += __shfl_xor(dDc, mask, 64);
        wsD += __shfl_xor(wsD, mask, 64);
    }

    if (lane == 0) {
        const float bgA = 1.f - wsA;
        const float bgD = 1.f - wsD;
        float* o = out + (size_t)ray * 9;
        o[0] = iA0 + bgA;
        o[1] = iA1 + bgA;
        o[2] = iA2 + bgA;
        o[3] = dAc;
        o[4] = wsA;
        o[5] = iD0 + bgD;
        o[6] = iD1 + bgD;
        o[7] = iD2 + bgD;
        o[8] = dDc;
    }
}

extern "C" void kernel_launch(void* const* d_in, const int* in_sizes, int n_in,
                              void* d_out, int out_size, void* d_ws, size_t ws_size,
                              hipStream_t stream) {
    const float* rays_o = (const float*)d_in[0];
    const float* rays_d = (const float*)d_in[1];
    const float* W1     = (const float*)d_in[2];
    const float* b1     = (const float*)d_in[3];
    const float* Wsig   = (const float*)d_in[4];
    const float* Wsig_d = (const float*)d_in[5];
    const float* Wc1    = (const float*)d_in[6];
    const float* bc1    = (const float*)d_in[7];
    const float* Wc2    = (const float*)d_in[8];
    const float* Wc2_d  = (const float*)d_in[9];
    const int* num_steps = (const int*)d_in[10];

    const int N = in_sizes[0] / 3;
    float* out = (float*)d_out;
    u32*   ws  = (u32*)d_ws;    // 6 KB used

    hipLaunchKernelGGL(nerf_prep_kernel, dim3(1), dim3(256), 0, stream,
                       W1, b1, Wsig, Wsig_d, Wc1, bc1, Wc2, Wc2_d, ws);

    const int blocks = (N + 3) / 4;   // 4 rays (waves) per block
    hipLaunchKernelGGL(nerf_render_kernel, dim3(blocks), dim3(256), 0, stream,
                       rays_o, rays_d, ws, num_steps, out, N);
}

// Round 10
// 79.612 us; speedup vs baseline: 1.1305x; 1.1305x over previous
//
#include <hip/hip_runtime.h>
#include <hip/hip_bf16.h>

// NeRF surrogate renderer, MI355X — round 10: bisect/fix of R9's NaN.
// R9 changed 3 things at once; the un-verified one (v_cvt_pk_bf16_f32 inline
// asm) is the NaN suspect. This round keeps the two logic-verified changes:
//   (a) slot-permuted A2 -> B2 = {p0[2ch],p1[2ch],p0[2ch+1],p1[2ch+1]}, zero
//       lane exchange (unit h*16+4g+rr at k-slot 8g+kk, both sides verified)
//   (b) SoA stash rows (stride 132): 2/4-way bank conflicts only
// and reverts packing to the R8-PROVEN pkbf RNE bit-twiddle (no inline asm).

typedef float  f32x4  __attribute__((ext_vector_type(4)));
typedef short  bf16x8 __attribute__((ext_vector_type(8)));
typedef unsigned int u32;

__device__ __forceinline__ float fast_rcp(float x){ return __builtin_amdgcn_rcpf(x); }
__device__ __forceinline__ float softplus_f(float x){
    float e = __expf(-fabsf(x));
    return fmaxf(x,0.f) + __logf(1.f+e);
}
__device__ __forceinline__ float sigmoid_f(float x){ return fast_rcp(1.f+__expf(-x)); }

// RNE bf16 pack, proven in R8 (absmax 0.0039)
__device__ __forceinline__ u32 bfr_hi(float f){
    u32 u = __float_as_uint(f);
    return (u + 0x7FFFu + ((u>>16)&1u)) & 0xFFFF0000u;
}
__device__ __forceinline__ u32 pkbf(float lo, float hi){
    return (bfr_hi(lo)>>16) | bfr_hi(hi);
}

// ---- prep: emit fragment-ready bf16 dword images into d_ws ----
// ws[0..1023]    : A1 frags, [ut(4)][lane(64)][dw(4)]  (GEMM1 A = W1ext)
// ws[1024..1535] : A2 frags, [ch(2)][lane(64)][dw(4)]  (GEMM2 A, slot-permuted)
__global__ __launch_bounds__(256)
void nerf_prep_kernel(const float* __restrict__ W1, const float* __restrict__ b1,
                      const float* __restrict__ Wsig, const float* __restrict__ Wsig_d,
                      const float* __restrict__ Wc1, const float* __restrict__ bc1,
                      const float* __restrict__ Wc2, const float* __restrict__ Wc2_d,
                      u32* __restrict__ ws)
{
    const int q0 = threadIdx.x;
#pragma unroll
    for (int k = 0; k < 6; ++k) {
        const int q = q0 + k*256;          // 0..1535
        u32 val = 0u;
        if (q < 1024) {                    // A1: row m=unit (lane&15), k=8g+i feats
            const int ut = q>>8, rem = q&255, lane = rem>>2, dw = rem&3;
            const int g = lane>>4, m = lane&15;
            if (g == 0) {                  // k>=8 lanes stay zero (K padding)
                float w[8];
                if (ut < 2) { const int u = ut*16 + m;
                    w[0]=W1[u];  w[1]=W1[32+u];  w[2]=W1[64+u];  w[3]=b1[u];
                    w[4]=0.f;    w[5]=0.f;       w[6]=0.f;       w[7]=0.f;
                } else {        const int u = (ut-2)*16 + m;
                    w[0]=Wc1[u]; w[1]=Wc1[32+u]; w[2]=Wc1[64+u]; w[3]=bc1[u];
                    w[4]=Wc1[96+u]; w[5]=Wc1[128+u]; w[6]=Wc1[160+u]; w[7]=0.f;
                }
                val = pkbf(w[2*dw], w[2*dw+1]);
            }
        } else {                           // A2: row o=output (lane&15), slot-permuted k
            const int q2 = q-1024, ch = q2>>8, rem = q2&255, lane = rem>>2, dw = rem&3;
            const int g = lane>>4, o = lane&15;
            float w[2];
#pragma unroll
            for (int e = 0; e < 2; ++e) {
                const int kk = 2*dw + e;              // 0..7
                const int h = kk>>2, rr = kk&3;
                const int u_local = h*16 + g*4 + rr;  // slot -> actual unit (within 32)
                float v = 0.f;
                if (ch == 0) {             // h-trunk units -> sigma heads
                    if (o == 0) v = Wsig[u_local];
                    else if (o == 1) v = Wsig_d[u_local];
                } else {                   // hc-trunk units -> color heads
                    if (o >= 2 && o <= 4) v = Wc2[u_local*3 + (o-2)];
                    else if (o >= 5 && o <= 7) v = Wc2_d[u_local*3 + (o-5)];
                }
                w[e] = v;
            }
            val = pkbf(w[0], w[1]);
        }
        ws[q] = val;
    }
}

#define SROW 132   // stash row stride (floats)

// ---- main: 1 wave per ray, 4 rays per 256-thread block ----
__global__ __launch_bounds__(256, 4)
void nerf_render_kernel(const float* __restrict__ rays_o,
                        const float* __restrict__ rays_d,
                        const u32*  __restrict__ wsm,
                        const int*  __restrict__ num_steps,
                        float* __restrict__ out,
                        int N)
{
    __shared__ float stash[4][8 * SROW];   // per-wave SoA: [out row][t]

    const int tid  = threadIdx.x;
    const int wid  = tid>>6, lane = tid&63;
    const int ray  = blockIdx.x*4 + wid;
    if (ray >= N) return;
    const int T = num_steps[0];
    const int g = lane>>4, c = lane&15;

    // loop-invariant weight fragments
    const uint4* wsv = (const uint4*)wsm;
    uint4 a1u[4], a2u[2];
#pragma unroll
    for (int ut = 0; ut < 4; ++ut) a1u[ut] = wsv[ut*64 + lane];
#pragma unroll
    for (int ch = 0; ch < 2; ++ch) a2u[ch] = wsv[256 + ch*64 + lane];

    // ray setup
    const float ox = rays_o[ray*3+0], oy = rays_o[ray*3+1], oz = rays_o[ray*3+2];
    const float rdx = rays_d[ray*3+0], rdy = rays_d[ray*3+1], rdz = rays_d[ray*3+2];
    const float rn = rsqrtf(rdx*rdx + rdy*rdy + rdz*rdz);
    const float dx = rdx*rn, dy = rdy*rn, dz = rdz*rn;

    const float ix = 1.0f/dx, iy = 1.0f/dy, iz = 1.0f/dz;
    const float t1x = (-1.f-ox)*ix, t2x = (1.f-ox)*ix;
    const float t1y = (-1.f-oy)*iy, t2y = (1.f-oy)*iy;
    const float t1z = (-1.f-oz)*iz, t2z = (1.f-oz)*iz;
    float nearv = fmaxf(fmaxf(fminf(t1x,t2x), fminf(t1y,t2y)), fminf(t1z,t2z));
    float farv  = fminf(fminf(fmaxf(t1x,t2x), fmaxf(t1y,t2y)), fmaxf(t1z,t2z));
    nearv = fmaxf(nearv, 0.2f);
    farv  = fmaxf(farv, nearv + 1e-6f);

    const float span    = farv - nearv;
    const float stepz   = (T > 1) ? span/(float)(T-1) : 0.f;
    const float inv_tm1 = (T > 1) ? 1.f/(float)(T-1) : 0.f;
    const float last_dt = span/(float)T;

    const u32 dirw0 = pkbf(dx, dy);
    const u32 dirw1 = pkbf(dz, 0.f);

    float* sb = stash[wid];
    int ntiles = (T + 15) >> 4;
    if (ntiles > 8) ntiles = 8;

    for (int tt = 0; tt < ntiles; ++tt) {
        const int t0 = tt*16;
        // B1 fragment: col=sample c, k=feats [x,y,z,1,dx,dy,dz,0] (bf16)
        const float zv = fmaf(stepz, (float)(t0 + c), nearv);
        const float X = fminf(fmaxf(fmaf(dx, zv, ox), -1.f), 1.f);
        const float Y = fminf(fmaxf(fmaf(dy, zv, oy), -1.f), 1.f);
        const float Z = fminf(fmaxf(fmaf(dz, zv, oz), -1.f), 1.f);
        uint4 b1u;
        b1u.x = pkbf(X, Y);
        b1u.y = pkbf(Z, 1.0f);
        b1u.z = dirw0;
        b1u.w = dirw1;
        const bf16x8 b1f = __builtin_bit_cast(bf16x8, b1u);

        // GEMM1: trunk[64 units][16 samples]
        f32x4 acc1[4];
#pragma unroll
        for (int ut = 0; ut < 4; ++ut) {
            acc1[ut] = __builtin_amdgcn_mfma_f32_16x16x32_bf16(
                __builtin_bit_cast(bf16x8, a1u[ut]), b1f,
                (f32x4){0.f,0.f,0.f,0.f}, 0, 0, 0);
        }

        // relu + RNE pair packs
        u32 p0[4], p1[4];
#pragma unroll
        for (int ut = 0; ut < 4; ++ut) {
            const float v0 = fmaxf(acc1[ut].x, 0.f);
            const float v1 = fmaxf(acc1[ut].y, 0.f);
            const float v2 = fmaxf(acc1[ut].z, 0.f);
            const float v3 = fmaxf(acc1[ut].w, 0.f);
            p0[ut] = pkbf(v0, v1);
            p1[ut] = pkbf(v2, v3);
        }

        // GEMM2: B2 directly from packs (slot permutation baked into A2)
        f32x4 acc2 = {0.f,0.f,0.f,0.f};
#pragma unroll
        for (int ch = 0; ch < 2; ++ch) {
            uint4 b2u;
            b2u.x = p0[2*ch];
            b2u.y = p1[2*ch];
            b2u.z = p0[2*ch+1];
            b2u.w = p1[2*ch+1];
            acc2 = __builtin_amdgcn_mfma_f32_16x16x32_bf16(
                __builtin_bit_cast(bf16x8, a2u[ch]),
                __builtin_bit_cast(bf16x8, b2u), acc2, 0, 0, 0);
        }

        // stash SoA: out row o = g*4+r, sample t0+c (rows 0..7 live)
        if (g < 2) {
            const int o = g*4;
            sb[(o+0)*SROW + t0 + c] = acc2.x;
            sb[(o+1)*SROW + t0 + c] = acc2.y;
            sb[(o+2)*SROW + t0 + c] = acc2.z;
            sb[(o+3)*SROW + t0 + c] = acc2.w;
        }
    }

    // epilogue: lane owns samples [lane*spl, lane*spl+spl)
    float iA0=0.f,iA1=0.f,iA2=0.f,dAc=0.f,wsA=0.f,TAx=1.f;
    float iD0=0.f,iD1=0.f,iD2=0.f,dDc=0.f,wsD=0.f,TDx=1.f;
    const int spl = (T + 63) >> 6;
    for (int k2 = 0; k2 < spl; ++k2) {
        const int t = lane*spl + k2;
        if (t < T) {
            const float vsA  = sb[0*SROW + t];
            const float vsD  = sb[1*SROW + t];
            const float vr0A = sb[2*SROW + t];
            const float vr1A = sb[3*SROW + t];
            const float vr2A = sb[4*SROW + t];
            const float vr0D = sb[5*SROW + t];
            const float vr1D = sb[6*SROW + t];
            const float vr2D = sb[7*SROW + t];
            const float dneg = (t < T-1) ? -stepz : -last_dt;
            const float z01  = (float)t * inv_tm1;

            const float sigA = softplus_f(vsA);
            const float qA = __expf(dneg*sigA);
            const float wA = TAx - TAx*qA; TAx *= qA;
            iA0 = fmaf(wA, sigmoid_f(vr0A), iA0);
            iA1 = fmaf(wA, sigmoid_f(vr1A), iA1);
            iA2 = fmaf(wA, sigmoid_f(vr2A), iA2);
            dAc = fmaf(wA, z01, dAc); wsA += wA;

            const float sigD = softplus_f(vsD);
            const float qD = __expf(dneg*sigD);
            const float wD = TDx - TDx*qD; TDx *= qD;
            iD0 = fmaf(wD, sigmoid_f(vr0D), iD0);
            iD1 = fmaf(wD, sigmoid_f(vr1D), iD1);
            iD2 = fmaf(wD, sigmoid_f(vr2D), iD2);
            dDc = fmaf(wD, z01, dDc); wsD += wD;
        }
    }

    // width-64 exclusive prefix product of transmittance, scale, butterfly-sum
    float scanA = TAx, scanD = TDx;
#pragma unroll
    for (int off = 1; off < 64; off <<= 1) {
        const float tA_ = __shfl_up(scanA, off, 64);
        const float tD_ = __shfl_up(scanD, off, 64);
        if (lane >= off) { scanA *= tA_; scanD *= tD_; }
    }
    float exA = __shfl_up(scanA, 1, 64);
    float exD = __shfl_up(scanD, 1, 64);
    if (lane == 0) { exA = 1.f; exD = 1.f; }

    iA0 *= exA; iA1 *= exA; iA2 *= exA; dAc *= exA; wsA *= exA;
    iD0 *= exD; iD1 *= exD; iD2 *= exD; dDc *= exD; wsD *= exD;

#pragma unroll
    for (int mask = 1; mask < 64; mask <<= 1) {
        iA0 += __shfl_xor(iA0, mask, 64);
        iA1 += __shfl_xor(iA1, mask, 64);
        iA2 += __shfl_xor(iA2, mask, 64);
        dAc += __shfl_xor(dAc, mask, 64);
        wsA += __shfl_xor(wsA, mask, 64);
        iD0 += __shfl_xor(iD0, mask, 64);
        iD1 += __shfl_xor(iD1, mask, 64);
        iD2 += __shfl_xor(iD2, mask, 64);
        dDc += __shfl_xor(dDc, mask, 64);
        wsD += __shfl_xor(wsD, mask, 64);
    }

    if (lane == 0) {
        const float bgA = 1.f - wsA;
        const float bgD = 1.f - wsD;
        float* o = out + (size_t)ray * 9;
        o[0] = iA0 + bgA;
        o[1] = iA1 + bgA;
        o[2] = iA2 + bgA;
        o[3] = dAc;
        o[4] = wsA;
        o[5] = iD0 + bgD;
        o[6] = iD1 + bgD;
        o[7] = iD2 + bgD;
        o[8] = dDc;
    }
}

extern "C" void kernel_launch(void* const* d_in, const int* in_sizes, int n_in,
                              void* d_out, int out_size, void* d_ws, size_t ws_size,
                              hipStream_t stream) {
    const float* rays_o = (const float*)d_in[0];
    const float* rays_d = (const float*)d_in[1];
    const float* W1     = (const float*)d_in[2];
    const float* b1     = (const float*)d_in[3];
    const float* Wsig   = (const float*)d_in[4];
    const float* Wsig_d = (const float*)d_in[5];
    const float* Wc1    = (const float*)d_in[6];
    const float* bc1    = (const float*)d_in[7];
    const float* Wc2    = (const float*)d_in[8];
    const float* Wc2_d  = (const float*)d_in[9];
    const int* num_steps = (const int*)d_in[10];

    const int N = in_sizes[0] / 3;
    float* out = (float*)d_out;
    u32*   ws  = (u32*)d_ws;    // 6 KB used

    hipLaunchKernelGGL(nerf_prep_kernel, dim3(1), dim3(256), 0, stream,
                       W1, b1, Wsig, Wsig_d, Wc1, bc1, Wc2, Wc2_d, ws);

    const int blocks = (N + 3) / 4;   // 4 rays (waves) per block
    hipLaunchKernelGGL(nerf_render_kernel, dim3(blocks), dim3(256), 0, stream,
                       rays_o, rays_d, ws, num_steps, out, N);
}

// Round 12
// 68.642 us; speedup vs baseline: 1.3111x; 1.1598x over previous
//
#include <hip/hip_runtime.h>
#include <hip/hip_bf16.h>

// NeRF surrogate renderer, MI355X — round 12: R11 retry with legal pin.
// R11 failed to compile: "+v" tied constraints on uint4 (vector) operands are
// unsupported ("tied indirect register inputs"). Fix: pin the 24 component
// dwords individually. Experiment content unchanged: (1) 3-op round-half-up
// pack via __builtin_amdgcn_perm, (2) 8-tile full unroll for T=128,
// (3) pinned weight fragments, (4) __launch_bounds__(256,6).

typedef float  f32x4  __attribute__((ext_vector_type(4)));
typedef short  bf16x8 __attribute__((ext_vector_type(8)));
typedef unsigned int u32;

__device__ __forceinline__ float fast_rcp(float x){ return __builtin_amdgcn_rcpf(x); }
__device__ __forceinline__ float softplus_f(float x){
    float e = __expf(-fabsf(x));
    return fmaxf(x,0.f) + __logf(1.f+e);
}
__device__ __forceinline__ float sigmoid_f(float x){ return fast_rcp(1.f+__expf(-x)); }

// hot-path pack: round-half-up + byte-select (3 VALU ops)
__device__ __forceinline__ u32 pkrn(float lo, float hi){
    const u32 a = __float_as_uint(lo) + 0x8000u;
    const u32 b = __float_as_uint(hi) + 0x8000u;
    // v_perm_b32: result bytes {b[2],b[3],a[2],a[3]} -> (bf16(hi)<<16)|bf16(lo)
    return __builtin_amdgcn_perm(b, a, 0x07060302u);
}

// exact RNE pack for the (cold) prep kernel
__device__ __forceinline__ u32 bfr_hi(float f){
    u32 u = __float_as_uint(f);
    return (u + 0x7FFFu + ((u>>16)&1u)) & 0xFFFF0000u;
}
__device__ __forceinline__ u32 pkbf(float lo, float hi){
    return (bfr_hi(lo)>>16) | bfr_hi(hi);
}

// ---- prep: emit fragment-ready bf16 dword images into d_ws ----
// ws[0..1023]    : A1 frags, [ut(4)][lane(64)][dw(4)]  (GEMM1 A = W1ext)
// ws[1024..1535] : A2 frags, [ch(2)][lane(64)][dw(4)]  (GEMM2 A, slot-permuted)
__global__ __launch_bounds__(256)
void nerf_prep_kernel(const float* __restrict__ W1, const float* __restrict__ b1,
                      const float* __restrict__ Wsig, const float* __restrict__ Wsig_d,
                      const float* __restrict__ Wc1, const float* __restrict__ bc1,
                      const float* __restrict__ Wc2, const float* __restrict__ Wc2_d,
                      u32* __restrict__ ws)
{
    const int q0 = threadIdx.x;
#pragma unroll
    for (int k = 0; k < 6; ++k) {
        const int q = q0 + k*256;          // 0..1535
        u32 val = 0u;
        if (q < 1024) {                    // A1: row m=unit (lane&15), k=8g+i feats
            const int ut = q>>8, rem = q&255, lane = rem>>2, dw = rem&3;
            const int g = lane>>4, m = lane&15;
            if (g == 0) {                  // k>=8 lanes stay zero (K padding)
                float w[8];
                if (ut < 2) { const int u = ut*16 + m;
                    w[0]=W1[u];  w[1]=W1[32+u];  w[2]=W1[64+u];  w[3]=b1[u];
                    w[4]=0.f;    w[5]=0.f;       w[6]=0.f;       w[7]=0.f;
                } else {        const int u = (ut-2)*16 + m;
                    w[0]=Wc1[u]; w[1]=Wc1[32+u]; w[2]=Wc1[64+u]; w[3]=bc1[u];
                    w[4]=Wc1[96+u]; w[5]=Wc1[128+u]; w[6]=Wc1[160+u]; w[7]=0.f;
                }
                val = pkbf(w[2*dw], w[2*dw+1]);
            }
        } else {                           // A2: row o=output (lane&15), slot-permuted k
            const int q2 = q-1024, ch = q2>>8, rem = q2&255, lane = rem>>2, dw = rem&3;
            const int g = lane>>4, o = lane&15;
            float w[2];
#pragma unroll
            for (int e = 0; e < 2; ++e) {
                const int kk = 2*dw + e;              // 0..7
                const int h = kk>>2, rr = kk&3;
                const int u_local = h*16 + g*4 + rr;  // slot -> actual unit (within 32)
                float v = 0.f;
                if (ch == 0) {             // h-trunk units -> sigma heads
                    if (o == 0) v = Wsig[u_local];
                    else if (o == 1) v = Wsig_d[u_local];
                } else {                   // hc-trunk units -> color heads
                    if (o >= 2 && o <= 4) v = Wc2[u_local*3 + (o-2)];
                    else if (o >= 5 && o <= 7) v = Wc2_d[u_local*3 + (o-5)];
                }
                w[e] = v;
            }
            val = pkbf(w[0], w[1]);
        }
        ws[q] = val;
    }
}

#define SROW 132   // stash row stride (floats)

// ---- main: 1 wave per ray, 4 rays per 256-thread block ----
__global__ __launch_bounds__(256, 6)
void nerf_render_kernel(const float* __restrict__ rays_o,
                        const float* __restrict__ rays_d,
                        const u32*  __restrict__ wsm,
                        const int*  __restrict__ num_steps,
                        float* __restrict__ out,
                        int N)
{
    __shared__ float stash[4][8 * SROW];   // per-wave SoA: [out row][t]

    const int tid  = threadIdx.x;
    const int wid  = tid>>6, lane = tid&63;
    const int ray  = blockIdx.x*4 + wid;
    if (ray >= N) return;
    const int T = num_steps[0];
    const int g = lane>>4, c = lane&15;

    // loop-invariant weight fragments — loaded once, pinned in VGPRs
    const uint4* wsv = (const uint4*)wsm;
    uint4 a1u0 = wsv[0*64 + lane];
    uint4 a1u1 = wsv[1*64 + lane];
    uint4 a1u2 = wsv[2*64 + lane];
    uint4 a1u3 = wsv[3*64 + lane];
    uint4 a2u0 = wsv[256 + 0*64 + lane];
    uint4 a2u1 = wsv[256 + 1*64 + lane];
    asm volatile("" : "+v"(a1u0.x), "+v"(a1u0.y), "+v"(a1u0.z), "+v"(a1u0.w),
                      "+v"(a1u1.x), "+v"(a1u1.y), "+v"(a1u1.z), "+v"(a1u1.w),
                      "+v"(a1u2.x), "+v"(a1u2.y), "+v"(a1u2.z), "+v"(a1u2.w));
    asm volatile("" : "+v"(a1u3.x), "+v"(a1u3.y), "+v"(a1u3.z), "+v"(a1u3.w),
                      "+v"(a2u0.x), "+v"(a2u0.y), "+v"(a2u0.z), "+v"(a2u0.w),
                      "+v"(a2u1.x), "+v"(a2u1.y), "+v"(a2u1.z), "+v"(a2u1.w));

    // ray setup
    const float ox = rays_o[ray*3+0], oy = rays_o[ray*3+1], oz = rays_o[ray*3+2];
    const float rdx = rays_d[ray*3+0], rdy = rays_d[ray*3+1], rdz = rays_d[ray*3+2];
    const float rn = rsqrtf(rdx*rdx + rdy*rdy + rdz*rdz);
    const float dx = rdx*rn, dy = rdy*rn, dz = rdz*rn;

    const float ix = 1.0f/dx, iy = 1.0f/dy, iz = 1.0f/dz;
    const float t1x = (-1.f-ox)*ix, t2x = (1.f-ox)*ix;
    const float t1y = (-1.f-oy)*iy, t2y = (1.f-oy)*iy;
    const float t1z = (-1.f-oz)*iz, t2z = (1.f-oz)*iz;
    float nearv = fmaxf(fmaxf(fminf(t1x,t2x), fminf(t1y,t2y)), fminf(t1z,t2z));
    float farv  = fminf(fminf(fmaxf(t1x,t2x), fmaxf(t1y,t2y)), fmaxf(t1z,t2z));
    nearv = fmaxf(nearv, 0.2f);
    farv  = fmaxf(farv, nearv + 1e-6f);

    const float span    = farv - nearv;
    const float stepz   = (T > 1) ? span/(float)(T-1) : 0.f;
    const float inv_tm1 = (T > 1) ? 1.f/(float)(T-1) : 0.f;
    const float last_dt = span/(float)T;

    const u32 dirw0 = pkbf(dx, dy);    // exact RNE for ray-constant dirs
    const u32 dirw1 = pkbf(dz, 0.f);
    const float cf = (float)c;

    float* sb = stash[wid];

#define TILE(TT)                                                                  \
    {                                                                             \
        const int t0 = (TT)*16;                                                   \
        const float zv = fmaf(stepz, cf + (float)t0, nearv);                      \
        const float X = fminf(fmaxf(fmaf(dx, zv, ox), -1.f), 1.f);                \
        const float Y = fminf(fmaxf(fmaf(dy, zv, oy), -1.f), 1.f);                \
        const float Z = fminf(fmaxf(fmaf(dz, zv, oz), -1.f), 1.f);                \
        uint4 b1u;                                                                \
        b1u.x = pkrn(X, Y);                                                       \
        b1u.y = pkrn(Z, 1.0f);                                                    \
        b1u.z = dirw0;                                                            \
        b1u.w = dirw1;                                                            \
        const bf16x8 b1f = __builtin_bit_cast(bf16x8, b1u);                       \
        f32x4 acc10 = __builtin_amdgcn_mfma_f32_16x16x32_bf16(                    \
            __builtin_bit_cast(bf16x8, a1u0), b1f, (f32x4){0.f,0.f,0.f,0.f},0,0,0);\
        f32x4 acc11 = __builtin_amdgcn_mfma_f32_16x16x32_bf16(                    \
            __builtin_bit_cast(bf16x8, a1u1), b1f, (f32x4){0.f,0.f,0.f,0.f},0,0,0);\
        f32x4 acc12 = __builtin_amdgcn_mfma_f32_16x16x32_bf16(                    \
            __builtin_bit_cast(bf16x8, a1u2), b1f, (f32x4){0.f,0.f,0.f,0.f},0,0,0);\
        f32x4 acc13 = __builtin_amdgcn_mfma_f32_16x16x32_bf16(                    \
            __builtin_bit_cast(bf16x8, a1u3), b1f, (f32x4){0.f,0.f,0.f,0.f},0,0,0);\
        const u32 p00 = pkrn(fmaxf(acc10.x,0.f), fmaxf(acc10.y,0.f));             \
        const u32 p10 = pkrn(fmaxf(acc10.z,0.f), fmaxf(acc10.w,0.f));             \
        const u32 p01 = pkrn(fmaxf(acc11.x,0.f), fmaxf(acc11.y,0.f));             \
        const u32 p11 = pkrn(fmaxf(acc11.z,0.f), fmaxf(acc11.w,0.f));             \
        const u32 p02 = pkrn(fmaxf(acc12.x,0.f), fmaxf(acc12.y,0.f));             \
        const u32 p12 = pkrn(fmaxf(acc12.z,0.f), fmaxf(acc12.w,0.f));             \
        const u32 p03 = pkrn(fmaxf(acc13.x,0.f), fmaxf(acc13.y,0.f));             \
        const u32 p13 = pkrn(fmaxf(acc13.z,0.f), fmaxf(acc13.w,0.f));             \
        uint4 b2a; b2a.x = p00; b2a.y = p10; b2a.z = p01; b2a.w = p11;            \
        uint4 b2b; b2b.x = p02; b2b.y = p12; b2b.z = p03; b2b.w = p13;            \
        f32x4 acc2 = __builtin_amdgcn_mfma_f32_16x16x32_bf16(                     \
            __builtin_bit_cast(bf16x8, a2u0), __builtin_bit_cast(bf16x8, b2a),    \
            (f32x4){0.f,0.f,0.f,0.f}, 0, 0, 0);                                   \
        acc2 = __builtin_amdgcn_mfma_f32_16x16x32_bf16(                           \
            __builtin_bit_cast(bf16x8, a2u1), __builtin_bit_cast(bf16x8, b2b),    \
            acc2, 0, 0, 0);                                                       \
        if (g < 2) {                                                              \
            const int o = g*4;                                                    \
            sb[(o+0)*SROW + t0 + c] = acc2.x;                                     \
            sb[(o+1)*SROW + t0 + c] = acc2.y;                                     \
            sb[(o+2)*SROW + t0 + c] = acc2.z;                                     \
            sb[(o+3)*SROW + t0 + c] = acc2.w;                                     \
        }                                                                         \
    }

    if (T == 128) {
        TILE(0) TILE(1) TILE(2) TILE(3) TILE(4) TILE(5) TILE(6) TILE(7)
    } else {
        int ntiles = (T + 15) >> 4;
        if (ntiles > 8) ntiles = 8;
        for (int tt = 0; tt < ntiles; ++tt) TILE(tt)
    }
#undef TILE

    // epilogue: lane owns samples [lane*spl, lane*spl+spl)
    float iA0=0.f,iA1=0.f,iA2=0.f,dAc=0.f,wsA=0.f,TAx=1.f;
    float iD0=0.f,iD1=0.f,iD2=0.f,dDc=0.f,wsD=0.f,TDx=1.f;
    const int spl = (T + 63) >> 6;
    for (int k2 = 0; k2 < spl; ++k2) {
        const int t = lane*spl + k2;
        if (t < T) {
            const float vsA  = sb[0*SROW + t];
            const float vsD  = sb[1*SROW + t];
            const float vr0A = sb[2*SROW + t];
            const float vr1A = sb[3*SROW + t];
            const float vr2A = sb[4*SROW + t];
            const float vr0D = sb[5*SROW + t];
            const float vr1D = sb[6*SROW + t];
            const float vr2D = sb[7*SROW + t];
            const float dneg = (t < T-1) ? -stepz : -last_dt;
            const float z01  = (float)t * inv_tm1;

            const float sigA = softplus_f(vsA);
            const float qA = __expf(dneg*sigA);
            const float wA = TAx - TAx*qA; TAx *= qA;
            iA0 = fmaf(wA, sigmoid_f(vr0A), iA0);
            iA1 = fmaf(wA, sigmoid_f(vr1A), iA1);
            iA2 = fmaf(wA, sigmoid_f(vr2A), iA2);
            dAc = fmaf(wA, z01, dAc); wsA += wA;

            const float sigD = softplus_f(vsD);
            const float qD = __expf(dneg*sigD);
            const float wD = TDx - TDx*qD; TDx *= qD;
            iD0 = fmaf(wD, sigmoid_f(vr0D), iD0);
            iD1 = fmaf(wD, sigmoid_f(vr1D), iD1);
            iD2 = fmaf(wD, sigmoid_f(vr2D), iD2);
            dDc = fmaf(wD, z01, dDc); wsD += wD;
        }
    }

    // width-64 exclusive prefix product of transmittance, scale, butterfly-sum
    float scanA = TAx, scanD = TDx;
#pragma unroll
    for (int off = 1; off < 64; off <<= 1) {
        const float tA_ = __shfl_up(scanA, off, 64);
        const float tD_ = __shfl_up(scanD, off, 64);
        if (lane >= off) { scanA *= tA_; scanD *= tD_; }
    }
    float exA = __shfl_up(scanA, 1, 64);
    float exD = __shfl_up(scanD, 1, 64);
    if (lane == 0) { exA = 1.f; exD = 1.f; }

    iA0 *= exA; iA1 *= exA; iA2 *= exA; dAc *= exA; wsA *= exA;
    iD0 *= exD; iD1 *= exD; iD2 *= exD; dDc *= exD; wsD *= exD;

#pragma unroll
    for (int mask = 1; mask < 64; mask <<= 1) {
        iA0 += __shfl_xor(iA0, mask, 64);
        iA1 += __shfl_xor(iA1, mask, 64);
        iA2 += __shfl_xor(iA2, mask, 64);
        dAc += __shfl_xor(dAc, mask, 64);
        wsA += __shfl_xor(wsA, mask, 64);
        iD0 += __shfl_xor(iD0, mask, 64);
        iD1 += __shfl_xor(iD1, mask, 64);
        iD2 += __shfl_xor(iD2, mask, 64);
        dDc += __shfl_xor(dDc, mask, 64);
        wsD += __shfl_xor(wsD, mask, 64);
    }

    if (lane == 0) {
        const float bgA = 1.f - wsA;
        const float bgD = 1.f - wsD;
        float* o = out + (size_t)ray * 9;
        o[0] = iA0 + bgA;
        o[1] = iA1 + bgA;
        o[2] = iA2 + bgA;
        o[3] = dAc;
        o[4] = wsA;
        o[5] = iD0 + bgD;
        o[6] = iD1 + bgD;
        o[7] = iD2 + bgD;
        o[8] = dDc;
    }
}

extern "C" void kernel_launch(void* const* d_in, const int* in_sizes, int n_in,
                              void* d_out, int out_size, void* d_ws, size_t ws_size,
                              hipStream_t stream) {
    const float* rays_o = (const float*)d_in[0];
    const float* rays_d = (const float*)d_in[1];
    const float* W1     = (const float*)d_in[2];
    const float* b1     = (const float*)d_in[3];
    const float* Wsig   = (const float*)d_in[4];
    const float* Wsig_d = (const float*)d_in[5];
    const float* Wc1    = (const float*)d_in[6];
    const float* bc1    = (const float*)d_in[7];
    const float* Wc2    = (const float*)d_in[8];
    const float* Wc2_d  = (const float*)d_in[9];
    const int* num_steps = (const int*)d_in[10];

    const int N = in_sizes[0] / 3;
    float* out = (float*)d_out;
    u32*   ws  = (u32*)d_ws;    // 6 KB used

    hipLaunchKernelGGL(nerf_prep_kernel, dim3(1), dim3(256), 0, stream,
                       W1, b1, Wsig, Wsig_d, Wc1, bc1, Wc2, Wc2_d, ws);

    const int blocks = (N + 3) / 4;   // 4 rays (waves) per block
    hipLaunchKernelGGL(nerf_render_kernel, dim3(blocks), dim3(256), 0, stream,
                       rays_o, rays_d, ws, num_steps, out, N);
}

// Round 13
// 61.156 us; speedup vs baseline: 1.4716x; 1.1224x over previous
//
#include <hip/hip_runtime.h>
#include <hip/hip_bf16.h>

// NeRF surrogate renderer, MI355X — round 13: lane-per-ray composite.
// R12: 89% VALUBusy at 68us — per-ray overhead (width-64 scan + butterfly,
// ~74 shuffles) dominates. Restructure: wave = 64 rays (lane r = ray r),
// block = 4 waves = 4 sample-segments of the same 64 rays.
// Per 4-sample chunk: A) lane builds own-ray B1 columns -> posBuf (b128,
// stride 24 dw, bank-uniform); B) 16 unrolled MFMA tiles (4 rays x 4 samples,
// ds_read_b128 + compile-time offsets; stash stride 36 dw, bank-uniform);
// C) lane composites its own ray's 4 samples sequentially in registers.
// Zero shuffles. Segment combine via LDS (aliased, double barrier).

typedef float  f32x4  __attribute__((ext_vector_type(4)));
typedef short  bf16x8 __attribute__((ext_vector_type(8)));
typedef unsigned int u32;

__device__ __forceinline__ float fast_rcp(float x){ return __builtin_amdgcn_rcpf(x); }
__device__ __forceinline__ float softplus_f(float x){
    float e = __expf(-fabsf(x));
    return fmaxf(x,0.f) + __logf(1.f+e);
}
__device__ __forceinline__ float sigmoid_f(float x){ return fast_rcp(1.f+__expf(-x)); }

// hot-path pack: round-half-up + byte-select (3 VALU ops) — proven R12
__device__ __forceinline__ u32 pkrn(float lo, float hi){
    const u32 a = __float_as_uint(lo) + 0x8000u;
    const u32 b = __float_as_uint(hi) + 0x8000u;
    return __builtin_amdgcn_perm(b, a, 0x07060302u);
}
// exact RNE pack (cold paths)
__device__ __forceinline__ u32 bfr_hi(float f){
    u32 u = __float_as_uint(f);
    return (u + 0x7FFFu + ((u>>16)&1u)) & 0xFFFF0000u;
}
__device__ __forceinline__ u32 pkbf(float lo, float hi){
    return (bfr_hi(lo)>>16) | bfr_hi(hi);
}

// ---- prep: identical to R12 (proven) ----
__global__ __launch_bounds__(256)
void nerf_prep_kernel(const float* __restrict__ W1, const float* __restrict__ b1,
                      const float* __restrict__ Wsig, const float* __restrict__ Wsig_d,
                      const float* __restrict__ Wc1, const float* __restrict__ bc1,
                      const float* __restrict__ Wc2, const float* __restrict__ Wc2_d,
                      u32* __restrict__ ws)
{
    const int q0 = threadIdx.x;
#pragma unroll
    for (int k = 0; k < 6; ++k) {
        const int q = q0 + k*256;
        u32 val = 0u;
        if (q < 1024) {
            const int ut = q>>8, rem = q&255, lane = rem>>2, dw = rem&3;
            const int g = lane>>4, m = lane&15;
            if (g == 0) {
                float w[8];
                if (ut < 2) { const int u = ut*16 + m;
                    w[0]=W1[u];  w[1]=W1[32+u];  w[2]=W1[64+u];  w[3]=b1[u];
                    w[4]=0.f;    w[5]=0.f;       w[6]=0.f;       w[7]=0.f;
                } else {        const int u = (ut-2)*16 + m;
                    w[0]=Wc1[u]; w[1]=Wc1[32+u]; w[2]=Wc1[64+u]; w[3]=bc1[u];
                    w[4]=Wc1[96+u]; w[5]=Wc1[128+u]; w[6]=Wc1[160+u]; w[7]=0.f;
                }
                val = pkbf(w[2*dw], w[2*dw+1]);
            }
        } else {
            const int q2 = q-1024, ch = q2>>8, rem = q2&255, lane = rem>>2, dw = rem&3;
            const int g = lane>>4, o = lane&15;
            float w[2];
#pragma unroll
            for (int e = 0; e < 2; ++e) {
                const int kk = 2*dw + e;
                const int h = kk>>2, rr = kk&3;
                const int u_local = h*16 + g*4 + rr;
                float v = 0.f;
                if (ch == 0) {
                    if (o == 0) v = Wsig[u_local];
                    else if (o == 1) v = Wsig_d[u_local];
                } else {
                    if (o >= 2 && o <= 4) v = Wc2[u_local*3 + (o-2)];
                    else if (o >= 5 && o <= 7) v = Wc2_d[u_local*3 + (o-5)];
                }
                w[e] = v;
            }
            val = pkbf(w[0], w[1]);
        }
        ws[q] = val;
    }
}

#define PSTR 24   // posBuf ray stride (dwords): bank-uniform for tile reads
#define SSTR 36   // stash ray stride (dwords): bank-uniform for writes+reads
#define CSTR 52   // combine ray stride (dwords): bank-uniform

// ---- main: block = 4 waves = 64 rays x T samples (wave w = segment w) ----
__global__ __launch_bounds__(256, 2)
void nerf_render_kernel(const float* __restrict__ rays_o,
                        const float* __restrict__ rays_d,
                        const u32*  __restrict__ wsm,
                        const int*  __restrict__ num_steps,
                        float* __restrict__ out,
                        int N)
{
    __shared__ u32   posBuf[4][64*PSTR];   // 24 KB
    __shared__ float stash [4][64*SSTR];   // 36 KB
    float* comb = &stash[0][0];            // aliased: used only after barrier

    const int tid  = threadIdx.x;
    const int seg  = tid>>6, lane = tid&63;
    const int ray  = blockIdx.x*64 + lane;
    const int rayc = (ray < N) ? ray : (N-1);
    const int T = num_steps[0];
    const int g = lane>>4, c = lane&15;

    // weight fragments (R12 layout), pinned
    const uint4* wsv = (const uint4*)wsm;
    uint4 a1u0 = wsv[0*64 + lane];
    uint4 a1u1 = wsv[1*64 + lane];
    uint4 a1u2 = wsv[2*64 + lane];
    uint4 a1u3 = wsv[3*64 + lane];
    uint4 a2u0 = wsv[256 + 0*64 + lane];
    uint4 a2u1 = wsv[256 + 1*64 + lane];
    asm volatile("" : "+v"(a1u0.x), "+v"(a1u0.y), "+v"(a1u0.z), "+v"(a1u0.w),
                      "+v"(a1u1.x), "+v"(a1u1.y), "+v"(a1u1.z), "+v"(a1u1.w),
                      "+v"(a1u2.x), "+v"(a1u2.y), "+v"(a1u2.z), "+v"(a1u2.w));
    asm volatile("" : "+v"(a1u3.x), "+v"(a1u3.y), "+v"(a1u3.z), "+v"(a1u3.w),
                      "+v"(a2u0.x), "+v"(a2u0.y), "+v"(a2u0.z), "+v"(a2u0.w),
                      "+v"(a2u1.x), "+v"(a2u1.y), "+v"(a2u1.z), "+v"(a2u1.w));

    // own-ray setup (each wave duplicates for the same 64 rays — cheap)
    const float ox = rays_o[rayc*3+0], oy = rays_o[rayc*3+1], oz = rays_o[rayc*3+2];
    const float rdx = rays_d[rayc*3+0], rdy = rays_d[rayc*3+1], rdz = rays_d[rayc*3+2];
    const float rn = rsqrtf(rdx*rdx + rdy*rdy + rdz*rdz);
    const float dx = rdx*rn, dy = rdy*rn, dz = rdz*rn;

    const float ix = 1.0f/dx, iy = 1.0f/dy, iz = 1.0f/dz;
    const float t1x = (-1.f-ox)*ix, t2x = (1.f-ox)*ix;
    const float t1y = (-1.f-oy)*iy, t2y = (1.f-oy)*iy;
    const float t1z = (-1.f-oz)*iz, t2z = (1.f-oz)*iz;
    float nearv = fmaxf(fmaxf(fminf(t1x,t2x), fminf(t1y,t2y)), fminf(t1z,t2z));
    float farv  = fminf(fminf(fmaxf(t1x,t2x), fmaxf(t1y,t2y)), fmaxf(t1z,t2z));
    nearv = fmaxf(nearv, 0.2f);
    farv  = fmaxf(farv, nearv + 1e-6f);

    const float span    = farv - nearv;
    const float stepz   = (T > 1) ? span/(float)(T-1) : 0.f;
    const float inv_tm1 = (T > 1) ? 1.f/(float)(T-1) : 0.f;
    const float last_dt = span/(float)T;

    const u32 dirw0 = pkbf(dx, dy);
    const u32 dirw1 = pkbf(dz, 0.f);

    // segment bounds for this wave
    const int Sper = (T + 3) >> 2;
    const int segStart = seg * Sper;
    const int segEnd = (segStart + Sper < T) ? (segStart + Sper) : T;
    const int nch = (segEnd > segStart) ? ((segEnd - segStart + 3) >> 2) : 0;

    u32*   posW = posBuf[seg];
    float* stashW = stash[seg];

    // per-lane constant LDS offsets (dwords)
    const int posOff = (c>>2)*PSTR + (c&3)*4;           // tile-column read
    const int stOff  = (c>>2)*SSTR + (c&3)*8 + g*4;     // tile-output write

    // composite state (lane = ray)
    float iA0=0.f,iA1=0.f,iA2=0.f,dAc=0.f,wsA=0.f,TAx=1.f;
    float iD0=0.f,iD1=0.f,iD2=0.f,dDc=0.f,wsD=0.f,TDx=1.f;

    for (int cs = 0; cs < nch; ++cs) {
        const int t0 = segStart + cs*4;

        // ---- phase A: own-ray B1 columns for 4 samples -> posBuf ----
        const float tb = (float)t0;
#pragma unroll
        for (int i = 0; i < 4; ++i) {
            const float zv = fmaf(stepz, tb + (float)i, nearv);
            const float X = fminf(fmaxf(fmaf(dx, zv, ox), -1.f), 1.f);
            const float Y = fminf(fmaxf(fmaf(dy, zv, oy), -1.f), 1.f);
            const float Z = fminf(fmaxf(fmaf(dz, zv, oz), -1.f), 1.f);
            uint4 v;
            v.x = pkrn(X, Y);
            v.y = pkrn(Z, 1.0f);
            v.z = dirw0;
            v.w = dirw1;
            *(uint4*)&posW[lane*PSTR + i*4] = v;
        }

        // ---- phase B: 16 MFMA tiles (tile TAU = rays 4*TAU..4*TAU+3) ----
#define TILEB(TAU)                                                                \
        {                                                                         \
            const uint4 b1u = *(const uint4*)&posW[(TAU)*(4*PSTR) + posOff];      \
            const bf16x8 b1f = __builtin_bit_cast(bf16x8, b1u);                   \
            f32x4 acc10 = __builtin_amdgcn_mfma_f32_16x16x32_bf16(                \
                __builtin_bit_cast(bf16x8, a1u0), b1f,(f32x4){0.f,0.f,0.f,0.f},0,0,0);\
            f32x4 acc11 = __builtin_amdgcn_mfma_f32_16x16x32_bf16(                \
                __builtin_bit_cast(bf16x8, a1u1), b1f,(f32x4){0.f,0.f,0.f,0.f},0,0,0);\
            f32x4 acc12 = __builtin_amdgcn_mfma_f32_16x16x32_bf16(                \
                __builtin_bit_cast(bf16x8, a1u2), b1f,(f32x4){0.f,0.f,0.f,0.f},0,0,0);\
            f32x4 acc13 = __builtin_amdgcn_mfma_f32_16x16x32_bf16(                \
                __builtin_bit_cast(bf16x8, a1u3), b1f,(f32x4){0.f,0.f,0.f,0.f},0,0,0);\
            const u32 p00 = pkrn(fmaxf(acc10.x,0.f), fmaxf(acc10.y,0.f));         \
            const u32 p10 = pkrn(fmaxf(acc10.z,0.f), fmaxf(acc10.w,0.f));         \
            const u32 p01 = pkrn(fmaxf(acc11.x,0.f), fmaxf(acc11.y,0.f));         \
            const u32 p11 = pkrn(fmaxf(acc11.z,0.f), fmaxf(acc11.w,0.f));         \
            const u32 p02 = pkrn(fmaxf(acc12.x,0.f), fmaxf(acc12.y,0.f));         \
            const u32 p12 = pkrn(fmaxf(acc12.z,0.f), fmaxf(acc12.w,0.f));         \
            const u32 p03 = pkrn(fmaxf(acc13.x,0.f), fmaxf(acc13.y,0.f));         \
            const u32 p13 = pkrn(fmaxf(acc13.z,0.f), fmaxf(acc13.w,0.f));         \
            uint4 b2a; b2a.x = p00; b2a.y = p10; b2a.z = p01; b2a.w = p11;        \
            uint4 b2b; b2b.x = p02; b2b.y = p12; b2b.z = p03; b2b.w = p13;        \
            f32x4 acc2 = __builtin_amdgcn_mfma_f32_16x16x32_bf16(                 \
                __builtin_bit_cast(bf16x8, a2u0), __builtin_bit_cast(bf16x8, b2a),\
                (f32x4){0.f,0.f,0.f,0.f}, 0, 0, 0);                               \
            acc2 = __builtin_amdgcn_mfma_f32_16x16x32_bf16(                       \
                __builtin_bit_cast(bf16x8, a2u1), __builtin_bit_cast(bf16x8, b2b),\
                acc2, 0, 0, 0);                                                   \
            if (g < 2) {                                                          \
                *(f32x4*)&stashW[(TAU)*(4*SSTR) + stOff] = acc2;                  \
            }                                                                     \
        }
        TILEB(0)  TILEB(1)  TILEB(2)  TILEB(3)
        TILEB(4)  TILEB(5)  TILEB(6)  TILEB(7)
        TILEB(8)  TILEB(9)  TILEB(10) TILEB(11)
        TILEB(12) TILEB(13) TILEB(14) TILEB(15)
#undef TILEB

        // ---- phase C: composite own ray's 4 samples (sequential, in-reg) ----
#pragma unroll
        for (int t = 0; t < 4; ++t) {
            const int tg = t0 + t;
            if (tg < segEnd) {
                const f32x4 oA = *(const f32x4*)&stashW[lane*SSTR + t*8];
                const f32x4 oB = *(const f32x4*)&stashW[lane*SSTR + t*8 + 4];
                const float dneg = (tg < T-1) ? -stepz : -last_dt;
                const float z01  = (float)tg * inv_tm1;

                const float sigA = softplus_f(oA.x);
                const float qA = __expf(dneg*sigA);
                const float wA = TAx - TAx*qA; TAx *= qA;
                iA0 = fmaf(wA, sigmoid_f(oA.z), iA0);
                iA1 = fmaf(wA, sigmoid_f(oA.w), iA1);
                iA2 = fmaf(wA, sigmoid_f(oB.x), iA2);
                dAc = fmaf(wA, z01, dAc); wsA += wA;

                const float sigD = softplus_f(oA.y);
                const float qD = __expf(dneg*sigD);
                const float wD = TDx - TDx*qD; TDx *= qD;
                iD0 = fmaf(wD, sigmoid_f(oB.y), iD0);
                iD1 = fmaf(wD, sigmoid_f(oB.z), iD1);
                iD2 = fmaf(wD, sigmoid_f(oB.w), iD2);
                dDc = fmaf(wD, z01, dDc); wsD += wD;
            }
        }
    }

    // ---- combine the 4 waves' segment states (comb aliases stash) ----
    __syncthreads();   // all waves done with stash before aliased writes
    *(f32x4*)&comb[lane*CSTR + seg*12 + 0] = (f32x4){iA0, iA1, iA2, dAc};
    *(f32x4*)&comb[lane*CSTR + seg*12 + 4] = (f32x4){wsA, TAx, iD0, iD1};
    *(f32x4*)&comb[lane*CSTR + seg*12 + 8] = (f32x4){iD2, dDc, wsD, TDx};
    __syncthreads();

    if (seg == 0) {
        float tA = TAx, tD = TDx;
#pragma unroll
        for (int s = 1; s < 4; ++s) {
            const f32x4 v0 = *(const f32x4*)&comb[lane*CSTR + s*12 + 0];
            const f32x4 v1 = *(const f32x4*)&comb[lane*CSTR + s*12 + 4];
            const f32x4 v2 = *(const f32x4*)&comb[lane*CSTR + s*12 + 8];
            iA0 = fmaf(tA, v0.x, iA0);
            iA1 = fmaf(tA, v0.y, iA1);
            iA2 = fmaf(tA, v0.z, iA2);
            dAc = fmaf(tA, v0.w, dAc);
            wsA = fmaf(tA, v1.x, wsA);
            tA *= v1.y;
            iD0 = fmaf(tD, v1.z, iD0);
            iD1 = fmaf(tD, v1.w, iD1);
            iD2 = fmaf(tD, v2.x, iD2);
            dDc = fmaf(tD, v2.y, dDc);
            wsD = fmaf(tD, v2.z, wsD);
            tD *= v2.w;
        }
        if (ray < N) {
            const float bgA = 1.f - wsA;
            const float bgD = 1.f - wsD;
            float* o = out + (size_t)ray * 9;
            o[0] = iA0 + bgA;
            o[1] = iA1 + bgA;
            o[2] = iA2 + bgA;
            o[3] = dAc;
            o[4] = wsA;
            o[5] = iD0 + bgD;
            o[6] = iD1 + bgD;
            o[7] = iD2 + bgD;
            o[8] = dDc;
        }
    }
}

extern "C" void kernel_launch(void* const* d_in, const int* in_sizes, int n_in,
                              void* d_out, int out_size, void* d_ws, size_t ws_size,
                              hipStream_t stream) {
    const float* rays_o = (const float*)d_in[0];
    const float* rays_d = (const float*)d_in[1];
    const float* W1     = (const float*)d_in[2];
    const float* b1     = (const float*)d_in[3];
    const float* Wsig   = (const float*)d_in[4];
    const float* Wsig_d = (const float*)d_in[5];
    const float* Wc1    = (const float*)d_in[6];
    const float* bc1    = (const float*)d_in[7];
    const float* Wc2    = (const float*)d_in[8];
    const float* Wc2_d  = (const float*)d_in[9];
    const int* num_steps = (const int*)d_in[10];

    const int N = in_sizes[0] / 3;
    float* out = (float*)d_out;
    u32*   ws  = (u32*)d_ws;    // 6 KB used

    hipLaunchKernelGGL(nerf_prep_kernel, dim3(1), dim3(256), 0, stream,
                       W1, b1, Wsig, Wsig_d, Wc1, bc1, Wc2, Wc2_d, ws);

    const int blocks = (N + 63) / 64;   // 64 rays per block (4 waves)
    hipLaunchKernelGGL(nerf_render_kernel, dim3(blocks), dim3(256), 0, stream,
                       rays_o, rays_d, ws, num_steps, out, N);
}

// Round 14
// 57.244 us; speedup vs baseline: 1.5722x; 1.0683x over previous
//
#include <hip/hip_runtime.h>
#include <hip/hip_bf16.h>

// NeRF surrogate renderer, MI355X — round 14: occupancy fix (8 waves x 16 samples).
// R13: 61us, Occupancy 17% (grid=512 blocks -> 2 waves/SIMD), latency-bound on
// LDS chains; stride 24/36 bank plan was wrong (1.57e6 conflicts). This round:
// 512-thr blocks (8 waves, 16 samples each) -> 4096 waves = 4 waves/SIMD.
// 2-sample chunks (tile = 8 rays x 2 samples). Strides multiple-of-4 dwords
// (b128 needs 16B align): posBuf 8 dw (reads = 4c, 2-way), stash 20 dw
// (min-conflict writes/reads). 57.3 KB LDS/block. launch_bounds(512,4).

typedef float  f32x4  __attribute__((ext_vector_type(4)));
typedef short  bf16x8 __attribute__((ext_vector_type(8)));
typedef unsigned int u32;

__device__ __forceinline__ float fast_rcp(float x){ return __builtin_amdgcn_rcpf(x); }
__device__ __forceinline__ float softplus_f(float x){
    float e = __expf(-fabsf(x));
    return fmaxf(x,0.f) + __logf(1.f+e);
}
__device__ __forceinline__ float sigmoid_f(float x){ return fast_rcp(1.f+__expf(-x)); }

// hot-path pack: round-half-up + byte-select (3 VALU ops) — proven R12/R13
__device__ __forceinline__ u32 pkrn(float lo, float hi){
    const u32 a = __float_as_uint(lo) + 0x8000u;
    const u32 b = __float_as_uint(hi) + 0x8000u;
    return __builtin_amdgcn_perm(b, a, 0x07060302u);
}
// exact RNE pack (cold paths)
__device__ __forceinline__ u32 bfr_hi(float f){
    u32 u = __float_as_uint(f);
    return (u + 0x7FFFu + ((u>>16)&1u)) & 0xFFFF0000u;
}
__device__ __forceinline__ u32 pkbf(float lo, float hi){
    return (bfr_hi(lo)>>16) | bfr_hi(hi);
}

// ---- prep: identical to R12/R13 (proven) ----
__global__ __launch_bounds__(256)
void nerf_prep_kernel(const float* __restrict__ W1, const float* __restrict__ b1,
                      const float* __restrict__ Wsig, const float* __restrict__ Wsig_d,
                      const float* __restrict__ Wc1, const float* __restrict__ bc1,
                      const float* __restrict__ Wc2, const float* __restrict__ Wc2_d,
                      u32* __restrict__ ws)
{
    const int q0 = threadIdx.x;
#pragma unroll
    for (int k = 0; k < 6; ++k) {
        const int q = q0 + k*256;
        u32 val = 0u;
        if (q < 1024) {
            const int ut = q>>8, rem = q&255, lane = rem>>2, dw = rem&3;
            const int g = lane>>4, m = lane&15;
            if (g == 0) {
                float w[8];
                if (ut < 2) { const int u = ut*16 + m;
                    w[0]=W1[u];  w[1]=W1[32+u];  w[2]=W1[64+u];  w[3]=b1[u];
                    w[4]=0.f;    w[5]=0.f;       w[6]=0.f;       w[7]=0.f;
                } else {        const int u = (ut-2)*16 + m;
                    w[0]=Wc1[u]; w[1]=Wc1[32+u]; w[2]=Wc1[64+u]; w[3]=bc1[u];
                    w[4]=Wc1[96+u]; w[5]=Wc1[128+u]; w[6]=Wc1[160+u]; w[7]=0.f;
                }
                val = pkbf(w[2*dw], w[2*dw+1]);
            }
        } else {
            const int q2 = q-1024, ch = q2>>8, rem = q2&255, lane = rem>>2, dw = rem&3;
            const int g = lane>>4, o = lane&15;
            float w[2];
#pragma unroll
            for (int e = 0; e < 2; ++e) {
                const int kk = 2*dw + e;
                const int h = kk>>2, rr = kk&3;
                const int u_local = h*16 + g*4 + rr;
                float v = 0.f;
                if (ch == 0) {
                    if (o == 0) v = Wsig[u_local];
                    else if (o == 1) v = Wsig_d[u_local];
                } else {
                    if (o >= 2 && o <= 4) v = Wc2[u_local*3 + (o-2)];
                    else if (o >= 5 && o <= 7) v = Wc2_d[u_local*3 + (o-5)];
                }
                w[e] = v;
            }
            val = pkbf(w[0], w[1]);
        }
        ws[q] = val;
    }
}

#define PSTR 8     // posBuf ray stride (dw), mult of 4; reads at 4c = 2-way
#define SSTR 20    // stash ray stride (dw), mult of 4; min-conflict
#define WSTR 1792  // per-wave LDS dwords: 64*PSTR + 64*SSTR = 512 + 1280
#define CSTR 100   // combine ray stride (dw), mult of 4

// ---- main: block = 8 waves = 64 rays x T samples (wave w = segment w) ----
__global__ __launch_bounds__(512, 4)
void nerf_render_kernel(const float* __restrict__ rays_o,
                        const float* __restrict__ rays_d,
                        const u32*  __restrict__ wsm,
                        const int*  __restrict__ num_steps,
                        float* __restrict__ out,
                        int N)
{
    __shared__ u32 smem[8 * WSTR];   // 57 344 B

    const int tid  = threadIdx.x;
    const int seg  = tid>>6, lane = tid&63;    // seg 0..7
    const int ray  = blockIdx.x*64 + lane;
    const int rayc = (ray < N) ? ray : (N-1);
    const int T = num_steps[0];
    const int g = lane>>4, c = lane&15;

    u32*   posW   = smem + seg*WSTR;
    float* stashW = (float*)(smem + seg*WSTR + 64*PSTR);
    float* comb   = (float*)smem;    // aliased; used only after barrier

    // weight fragments (proven layout), pinned
    const uint4* wsv = (const uint4*)wsm;
    uint4 a1u0 = wsv[0*64 + lane];
    uint4 a1u1 = wsv[1*64 + lane];
    uint4 a1u2 = wsv[2*64 + lane];
    uint4 a1u3 = wsv[3*64 + lane];
    uint4 a2u0 = wsv[256 + 0*64 + lane];
    uint4 a2u1 = wsv[256 + 1*64 + lane];
    asm volatile("" : "+v"(a1u0.x), "+v"(a1u0.y), "+v"(a1u0.z), "+v"(a1u0.w),
                      "+v"(a1u1.x), "+v"(a1u1.y), "+v"(a1u1.z), "+v"(a1u1.w),
                      "+v"(a1u2.x), "+v"(a1u2.y), "+v"(a1u2.z), "+v"(a1u2.w));
    asm volatile("" : "+v"(a1u3.x), "+v"(a1u3.y), "+v"(a1u3.z), "+v"(a1u3.w),
                      "+v"(a2u0.x), "+v"(a2u0.y), "+v"(a2u0.z), "+v"(a2u0.w),
                      "+v"(a2u1.x), "+v"(a2u1.y), "+v"(a2u1.z), "+v"(a2u1.w));

    // own-ray setup (duplicated across the block's 8 waves — cheap)
    const float ox = rays_o[rayc*3+0], oy = rays_o[rayc*3+1], oz = rays_o[rayc*3+2];
    const float rdx = rays_d[rayc*3+0], rdy = rays_d[rayc*3+1], rdz = rays_d[rayc*3+2];
    const float rn = rsqrtf(rdx*rdx + rdy*rdy + rdz*rdz);
    const float dx = rdx*rn, dy = rdy*rn, dz = rdz*rn;

    const float ix = 1.0f/dx, iy = 1.0f/dy, iz = 1.0f/dz;
    const float t1x = (-1.f-ox)*ix, t2x = (1.f-ox)*ix;
    const float t1y = (-1.f-oy)*iy, t2y = (1.f-oy)*iy;
    const float t1z = (-1.f-oz)*iz, t2z = (1.f-oz)*iz;
    float nearv = fmaxf(fmaxf(fminf(t1x,t2x), fminf(t1y,t2y)), fminf(t1z,t2z));
    float farv  = fminf(fminf(fmaxf(t1x,t2x), fmaxf(t1y,t2y)), fmaxf(t1z,t2z));
    nearv = fmaxf(nearv, 0.2f);
    farv  = fmaxf(farv, nearv + 1e-6f);

    const float span    = farv - nearv;
    const float stepz   = (T > 1) ? span/(float)(T-1) : 0.f;
    const float inv_tm1 = (T > 1) ? 1.f/(float)(T-1) : 0.f;
    const float last_dt = span/(float)T;

    const u32 dirw0 = pkbf(dx, dy);
    const u32 dirw1 = pkbf(dz, 0.f);

    // segment bounds for this wave (8 segments)
    const int Sper = (T + 7) >> 3;
    const int segStart = seg * Sper;
    const int segEnd = (segStart + Sper < T) ? (segStart + Sper) : T;
    const int nch = (segEnd > segStart) ? ((segEnd - segStart + 1) >> 1) : 0;

    // per-lane constant LDS offsets (dwords)
    const int posOff = 4*c;                          // (c>>1)*PSTR + (c&1)*4
    const int stOff  = (c>>1)*SSTR + (c&1)*8 + g*4;  // tile-output write

    // composite state (lane = ray)
    float iA0=0.f,iA1=0.f,iA2=0.f,dAc=0.f,wsA=0.f,TAx=1.f;
    float iD0=0.f,iD1=0.f,iD2=0.f,dDc=0.f,wsD=0.f,TDx=1.f;

    for (int cs = 0; cs < nch; ++cs) {
        const int t0 = segStart + cs*2;

        // ---- phase A: own-ray B1 columns for 2 samples -> posBuf ----
#pragma unroll
        for (int i = 0; i < 2; ++i) {
            const float zv = fmaf(stepz, (float)(t0 + i), nearv);
            const float X = fminf(fmaxf(fmaf(dx, zv, ox), -1.f), 1.f);
            const float Y = fminf(fmaxf(fmaf(dy, zv, oy), -1.f), 1.f);
            const float Z = fminf(fmaxf(fmaf(dz, zv, oz), -1.f), 1.f);
            uint4 v;
            v.x = pkrn(X, Y);
            v.y = pkrn(Z, 1.0f);
            v.z = dirw0;
            v.w = dirw1;
            *(uint4*)&posW[lane*PSTR + i*4] = v;
        }

        // ---- phase B: 8 MFMA tiles (tile TAU = rays 8*TAU..8*TAU+7, 2 samples) ----
#define TILEB(TAU)                                                                \
        {                                                                         \
            const uint4 b1u = *(const uint4*)&posW[(TAU)*(8*PSTR) + posOff];      \
            const bf16x8 b1f = __builtin_bit_cast(bf16x8, b1u);                   \
            f32x4 acc10 = __builtin_amdgcn_mfma_f32_16x16x32_bf16(                \
                __builtin_bit_cast(bf16x8, a1u0), b1f,(f32x4){0.f,0.f,0.f,0.f},0,0,0);\
            f32x4 acc11 = __builtin_amdgcn_mfma_f32_16x16x32_bf16(                \
                __builtin_bit_cast(bf16x8, a1u1), b1f,(f32x4){0.f,0.f,0.f,0.f},0,0,0);\
            f32x4 acc12 = __builtin_amdgcn_mfma_f32_16x16x32_bf16(                \
                __builtin_bit_cast(bf16x8, a1u2), b1f,(f32x4){0.f,0.f,0.f,0.f},0,0,0);\
            f32x4 acc13 = __builtin_amdgcn_mfma_f32_16x16x32_bf16(                \
                __builtin_bit_cast(bf16x8, a1u3), b1f,(f32x4){0.f,0.f,0.f,0.f},0,0,0);\
            const u32 p00 = pkrn(fmaxf(acc10.x,0.f), fmaxf(acc10.y,0.f));         \
            const u32 p10 = pkrn(fmaxf(acc10.z,0.f), fmaxf(acc10.w,0.f));         \
            const u32 p01 = pkrn(fmaxf(acc11.x,0.f), fmaxf(acc11.y,0.f));         \
            const u32 p11 = pkrn(fmaxf(acc11.z,0.f), fmaxf(acc11.w,0.f));         \
            const u32 p02 = pkrn(fmaxf(acc12.x,0.f), fmaxf(acc12.y,0.f));         \
            const u32 p12 = pkrn(fmaxf(acc12.z,0.f), fmaxf(acc12.w,0.f));         \
            const u32 p03 = pkrn(fmaxf(acc13.x,0.f), fmaxf(acc13.y,0.f));         \
            const u32 p13 = pkrn(fmaxf(acc13.z,0.f), fmaxf(acc13.w,0.f));         \
            uint4 b2a; b2a.x = p00; b2a.y = p10; b2a.z = p01; b2a.w = p11;        \
            uint4 b2b; b2b.x = p02; b2b.y = p12; b2b.z = p03; b2b.w = p13;        \
            f32x4 acc2 = __builtin_amdgcn_mfma_f32_16x16x32_bf16(                 \
                __builtin_bit_cast(bf16x8, a2u0), __builtin_bit_cast(bf16x8, b2a),\
                (f32x4){0.f,0.f,0.f,0.f}, 0, 0, 0);                               \
            acc2 = __builtin_amdgcn_mfma_f32_16x16x32_bf16(                       \
                __builtin_bit_cast(bf16x8, a2u1), __builtin_bit_cast(bf16x8, b2b),\
                acc2, 0, 0, 0);                                                   \
            if (g < 2) {                                                          \
                *(f32x4*)&stashW[(TAU)*(8*SSTR) + stOff] = acc2;                  \
            }                                                                     \
        }
        TILEB(0) TILEB(1) TILEB(2) TILEB(3)
        TILEB(4) TILEB(5) TILEB(6) TILEB(7)
#undef TILEB

        // ---- phase C: composite own ray's 2 samples (sequential, in-reg) ----
#pragma unroll
        for (int t = 0; t < 2; ++t) {
            const int tg = t0 + t;
            if (tg < segEnd) {
                const f32x4 oA = *(const f32x4*)&stashW[lane*SSTR + t*8];
                const f32x4 oB = *(const f32x4*)&stashW[lane*SSTR + t*8 + 4];
                const float dneg = (tg < T-1) ? -stepz : -last_dt;
                const float z01  = (float)tg * inv_tm1;

                const float sigA = softplus_f(oA.x);
                const float qA = __expf(dneg*sigA);
                const float wA = TAx - TAx*qA; TAx *= qA;
                iA0 = fmaf(wA, sigmoid_f(oA.z), iA0);
                iA1 = fmaf(wA, sigmoid_f(oA.w), iA1);
                iA2 = fmaf(wA, sigmoid_f(oB.x), iA2);
                dAc = fmaf(wA, z01, dAc); wsA += wA;

                const float sigD = softplus_f(oA.y);
                const float qD = __expf(dneg*sigD);
                const float wD = TDx - TDx*qD; TDx *= qD;
                iD0 = fmaf(wD, sigmoid_f(oB.y), iD0);
                iD1 = fmaf(wD, sigmoid_f(oB.z), iD1);
                iD2 = fmaf(wD, sigmoid_f(oB.w), iD2);
                dDc = fmaf(wD, z01, dDc); wsD += wD;
            }
        }
    }

    // ---- combine the 8 waves' segment states (comb aliases smem) ----
    __syncthreads();
    *(f32x4*)&comb[lane*CSTR + seg*12 + 0] = (f32x4){iA0, iA1, iA2, dAc};
    *(f32x4*)&comb[lane*CSTR + seg*12 + 4] = (f32x4){wsA, TAx, iD0, iD1};
    *(f32x4*)&comb[lane*CSTR + seg*12 + 8] = (f32x4){iD2, dDc, wsD, TDx};
    __syncthreads();

    if (seg == 0) {
        float tA = TAx, tD = TDx;
#pragma unroll
        for (int s = 1; s < 8; ++s) {
            const f32x4 v0 = *(const f32x4*)&comb[lane*CSTR + s*12 + 0];
            const f32x4 v1 = *(const f32x4*)&comb[lane*CSTR + s*12 + 4];
            const f32x4 v2 = *(const f32x4*)&comb[lane*CSTR + s*12 + 8];
            iA0 = fmaf(tA, v0.x, iA0);
            iA1 = fmaf(tA, v0.y, iA1);
            iA2 = fmaf(tA, v0.z, iA2);
            dAc = fmaf(tA, v0.w, dAc);
            wsA = fmaf(tA, v1.x, wsA);
            tA *= v1.y;
            iD0 = fmaf(tD, v1.z, iD0);
            iD1 = fmaf(tD, v1.w, iD1);
            iD2 = fmaf(tD, v2.x, iD2);
            dDc = fmaf(tD, v2.y, dDc);
            wsD = fmaf(tD, v2.z, wsD);
            tD *= v2.w;
        }
        if (ray < N) {
            const float bgA = 1.f - wsA;
            const float bgD = 1.f - wsD;
            float* o = out + (size_t)ray * 9;
            o[0] = iA0 + bgA;
            o[1] = iA1 + bgA;
            o[2] = iA2 + bgA;
            o[3] = dAc;
            o[4] = wsA;
            o[5] = iD0 + bgD;
            o[6] = iD1 + bgD;
            o[7] = iD2 + bgD;
            o[8] = dDc;
        }
    }
}

extern "C" void kernel_launch(void* const* d_in, const int* in_sizes, int n_in,
                              void* d_out, int out_size, void* d_ws, size_t ws_size,
                              hipStream_t stream) {
    const float* rays_o = (const float*)d_in[0];
    const float* rays_d = (const float*)d_in[1];
    const float* W1     = (const float*)d_in[2];
    const float* b1     = (const float*)d_in[3];
    const float* Wsig   = (const float*)d_in[4];
    const float* Wsig_d = (const float*)d_in[5];
    const float* Wc1    = (const float*)d_in[6];
    const float* bc1    = (const float*)d_in[7];
    const float* Wc2    = (const float*)d_in[8];
    const float* Wc2_d  = (const float*)d_in[9];
    const int* num_steps = (const int*)d_in[10];

    const int N = in_sizes[0] / 3;
    float* out = (float*)d_out;
    u32*   ws  = (u32*)d_ws;    // 6 KB used

    hipLaunchKernelGGL(nerf_prep_kernel, dim3(1), dim3(256), 0, stream,
                       W1, b1, Wsig, Wsig_d, Wc1, bc1, Wc2, Wc2_d, ws);

    const int blocks = (N + 63) / 64;   // 64 rays per block (8 waves)
    hipLaunchKernelGGL(nerf_render_kernel, dim3(blocks), dim3(512), 0, stream,
                       rays_o, rays_d, ws, num_steps, out, N);
}